// Round 1
// baseline (251.830 us; speedup 1.0000x reference)
//
#include <hip/hip_runtime.h>
#include <math.h>

#define NIMG   48
#define H      512
#define W      512
#define CH     34
#define CHUNKS 16
#define LDSW   528
#define NTHR   256
#define NBLOCK (NIMG * CHUNKS)
#define NPIX   12582912.0f

__device__ __forceinline__ int refl(int x) {
    x = (x < 0) ? -x : x;
    return (x >= 512) ? (1022 - x) : x;
}

__global__ __launch_bounds__(NTHR, 2)
void ssim_main(const float* __restrict__ img1, const float* __restrict__ img2,
               float* __restrict__ partial) {
    __shared__ float s1[11][LDSW];
    __shared__ float s2[11][LDSW];
    __shared__ float wred[NTHR / 64];

    const int t     = threadIdx.x;
    const int img   = blockIdx.x >> 4;             // / CHUNKS
    const int chunk = blockIdx.x & (CHUNKS - 1);
    const int R0    = chunk * CH;
    const int rows_out = min(CH, H - R0);          // 34, last chunk 2
    const int G     = (rows_out + 20) / 11;        // ceil((rows_out+10)/11)

    const float* __restrict__ b1 = img1 + (size_t)img * (H * W);
    const float* __restrict__ b2 = img2 + (size_t)img * (H * W);

    // Gaussian weights (match reference: exp(-d^2/(2*1.5^2)) normalized)
    float g[11];
    {
        float s = 0.f;
#pragma unroll
        for (int i = 0; i < 11; ++i) {
            float d = (float)(i - 5);
            g[i] = expf(-d * d / 4.5f);
            s += g[i];
        }
        float inv = 1.f / s;
#pragma unroll
        for (int i = 0; i < 11; ++i) g[i] *= inv;
    }

    // pend[slot][2q+c]: pending vertical accumulators, q in {mu1,mu2,e11,e22,e12}
    float pend[11][10];
#pragma unroll
    for (int s_ = 0; s_ < 11; ++s_)
#pragma unroll
        for (int q = 0; q < 10; ++q) pend[s_][q] = 0.f;

    float acc = 0.f;
    const float C1 = 0.0001f, C2 = 0.0009f;

    for (int grp = 0; grp < G; ++grp) {
        __syncthreads();
        {   // stage 11 padded rows for both images
            int j0 = R0 - 5 + grp * 11;
#pragma unroll
            for (int p = 0; p < 11; ++p) {
                int jr = refl(j0 + p);
                const float* r1 = b1 + jr * W;
                const float* r2 = b2 + jr * W;
                for (int lc = t; lc < LDSW; lc += NTHR) {
                    int gc = refl(lc - 8);
                    s1[p][lc] = r1[gc];
                    s2[p][lc] = r2[gc];
                }
            }
        }
        __syncthreads();

#pragma unroll
        for (int p = 0; p < 11; ++p) {
            const int jj = grp * 11 + p;   // local h-row index; h-row j = R0-5+jj
            // ---- horizontal blur of 5 quantities for 2 columns (c0=2t, c1=2t+1)
            const float2* f1 = (const float2*)(&s1[p][0]);
            const float2* f2 = (const float2*)(&s2[p][0]);
            float xa[14], xb[14];
#pragma unroll
            for (int k = 0; k < 7; ++k) {
                float2 a = f1[t + 1 + k];
                float2 b = f2[t + 1 + k];
                xa[2 * k] = a.x; xa[2 * k + 1] = a.y;
                xb[2 * k] = b.x; xb[2 * k + 1] = b.y;
            }
            float h[10];
#pragma unroll
            for (int q = 0; q < 10; ++q) h[q] = 0.f;
#pragma unroll
            for (int i = 1; i <= 12; ++i) {
                float a = xa[i], b = xb[i];
                float aa = a * a, bb = b * b, ab = a * b;
                if (i <= 11) {               // col0 taps: x[1..11], weight g[i-1]
                    float w = g[i - 1];
                    h[0] = fmaf(w, a,  h[0]);
                    h[2] = fmaf(w, b,  h[2]);
                    h[4] = fmaf(w, aa, h[4]);
                    h[6] = fmaf(w, bb, h[6]);
                    h[8] = fmaf(w, ab, h[8]);
                }
                if (i >= 2) {                // col1 taps: x[2..12], weight g[i-2]
                    float w = g[i - 2];
                    h[1] = fmaf(w, a,  h[1]);
                    h[3] = fmaf(w, b,  h[3]);
                    h[5] = fmaf(w, aa, h[5]);
                    h[7] = fmaf(w, bb, h[7]);
                    h[9] = fmaf(w, ab, h[9]);
                }
            }

            // ---- vertical scatter into pending accumulators (weight g[d], d = jj - r_local)
#pragma unroll
            for (int s_ = 0; s_ < 11; ++s_) {
                const int d = (p - s_ + 11) % 11;    // compile-time after unroll
                if (d == 0) {                        // new output row starts here
#pragma unroll
                    for (int q = 0; q < 10; ++q) pend[s_][q] = g[0] * h[q];
                } else if (d == 10) {                // output row jj-10 completes
                    if (jj >= 10 && (jj - 10) < rows_out) {
                        float v[10];
#pragma unroll
                        for (int q = 0; q < 10; ++q) v[q] = fmaf(g[10], h[q], pend[s_][q]);
#pragma unroll
                        for (int c = 0; c < 2; ++c) {
                            float mu1 = v[0 + c], mu2 = v[2 + c];
                            float e11 = v[4 + c], e22 = v[6 + c], e12 = v[8 + c];
                            float mu1s = mu1 * mu1, mu2s = mu2 * mu2, m12 = mu1 * mu2;
                            float num = (2.f * m12 + C1) * (2.f * (e12 - m12) + C2);
                            float den = (mu1s + mu2s + C1) *
                                        ((e11 - mu1s) + (e22 - mu2s) + C2);
                            float ssim = num * __builtin_amdgcn_rcpf(den);
                            ssim = fminf(fmaxf(ssim, 0.f), 1.f);
                            acc += ssim;
                        }
                    }
                } else {
                    const float w = g[d];
#pragma unroll
                    for (int q = 0; q < 10; ++q) pend[s_][q] = fmaf(w, h[q], pend[s_][q]);
                }
            }
        }
    }

    // ---- block reduction -> one partial per block
#pragma unroll
    for (int off = 32; off > 0; off >>= 1) acc += __shfl_xor(acc, off);
    if ((t & 63) == 0) wred[t >> 6] = acc;
    __syncthreads();
    if (t == 0) {
        float tot = 0.f;
#pragma unroll
        for (int wv = 0; wv < NTHR / 64; ++wv) tot += wred[wv];
        partial[blockIdx.x] = tot;
    }
}

__global__ void ssim_finish(const float* __restrict__ partial, float* __restrict__ out) {
    float s = 0.f;
    for (int i = threadIdx.x; i < NBLOCK; i += 256) s += partial[i];
#pragma unroll
    for (int off = 32; off > 0; off >>= 1) s += __shfl_xor(s, off);
    __shared__ float wred[4];
    if ((threadIdx.x & 63) == 0) wred[threadIdx.x >> 6] = s;
    __syncthreads();
    if (threadIdx.x == 0)
        out[0] = 1.0f - (wred[0] + wred[1] + wred[2] + wred[3]) / NPIX;
}

extern "C" void kernel_launch(void* const* d_in, const int* in_sizes, int n_in,
                              void* d_out, int out_size, void* d_ws, size_t ws_size,
                              hipStream_t stream) {
    const float* img1 = (const float*)d_in[0];
    const float* img2 = (const float*)d_in[1];
    float* out = (float*)d_out;
    float* partial = (float*)d_ws;   // 768 floats, all written each launch
    ssim_main<<<NBLOCK, NTHR, 0, stream>>>(img1, img2, partial);
    ssim_finish<<<1, 256, 0, stream>>>(partial, out);
}